// Round 1
// baseline (263.731 us; speedup 1.0000x reference)
//
#include <hip/hip_runtime.h>
#include <stdint.h>

#define E 8
#define D 512
#define F 2048
#define NTOK 4096

typedef __attribute__((ext_vector_type(8))) short bf16x8;
typedef __attribute__((ext_vector_type(4))) float f32x4;
typedef unsigned short u16;

// ---------- workspace layout (bytes) ----------
#define WS_COUNTS   0                         // 8 ints (memset to 0)
#define WS_OFFSETS  64                        // 9 ints
#define WS_CURSORS  128                       // 8 ints
#define WS_IDX      256                       // 4096 ints
#define WS_PERM     (256 + 4*NTOK)            // 4096 ints
#define WS_XG       65536                     // bf16 [4096][512]  (gathered x)
#define WS_W1T      (WS_XG + 2*NTOK*D)        // bf16 [8][2048][512]  (W1^T)
#define WS_W2T      (WS_W1T + 2*E*D*F)        // bf16 [8][512][2048]  (W2^T)
#define WS_H        (WS_W2T + 2*E*D*F)        // bf16 [4096][2048]  (hidden)

static __device__ __forceinline__ u16 f2b(float f) {
  union { float f; unsigned u; } v; v.f = f;
  unsigned r = v.u + 0x7fffu + ((v.u >> 16) & 1u);   // RNE fp32->bf16
  return (u16)(r >> 16);
}

static __device__ __forceinline__ void gload16(const void* g, void* l) {
  __builtin_amdgcn_global_load_lds(
      (const __attribute__((address_space(1))) unsigned int*)g,
      (__attribute__((address_space(3))) unsigned int*)l, 16, 0, 0);
}

// ---------- gate: fp32-exact logits + argmax + per-expert count ----------
__global__ __launch_bounds__(256) void gate_k(const float* __restrict__ x,
                                              const float* __restrict__ Wg,
                                              const float* __restrict__ bg,
                                              int* __restrict__ idx,
                                              int* __restrict__ counts) {
  int tok = blockIdx.x * 4 + (threadIdx.x >> 6);   // one wave per token
  int l = threadIdx.x & 63;
  const float* xr = x + (size_t)tok * D;
  float acc[E];
#pragma unroll
  for (int e = 0; e < E; ++e) acc[e] = 0.f;
#pragma unroll
  for (int j = 0; j < 2; ++j) {
    float4 xv = *(const float4*)(xr + l * 8 + j * 4);
    float xs[4] = {xv.x, xv.y, xv.z, xv.w};
#pragma unroll
    for (int c = 0; c < 4; ++c) {
      int d = l * 8 + j * 4 + c;
      float4 w0 = *(const float4*)(Wg + d * 8);
      float4 w1 = *(const float4*)(Wg + d * 8 + 4);
      acc[0] += xs[c] * w0.x; acc[1] += xs[c] * w0.y;
      acc[2] += xs[c] * w0.z; acc[3] += xs[c] * w0.w;
      acc[4] += xs[c] * w1.x; acc[5] += xs[c] * w1.y;
      acc[6] += xs[c] * w1.z; acc[7] += xs[c] * w1.w;
    }
  }
#pragma unroll
  for (int off = 32; off; off >>= 1)
#pragma unroll
    for (int e = 0; e < E; ++e) acc[e] += __shfl_xor(acc[e], off, 64);
  if (l == 0) {
    float bv = acc[0] + bg[0]; int bi = 0;
#pragma unroll
    for (int e = 1; e < E; ++e) {           // strict > : first-max tie-break (matches argmax)
      float v = acc[e] + bg[e];
      if (v > bv) { bv = v; bi = e; }
    }
    idx[tok] = bi;
    atomicAdd(&counts[bi], 1);
  }
}

// ---------- tiny scan: counts -> offsets, cursors ----------
__global__ void scan_k(const int* __restrict__ counts, int* __restrict__ offsets,
                       int* __restrict__ cursors) {
  if (threadIdx.x == 0) {
    int s = 0;
    for (int e = 0; e < E; ++e) { offsets[e] = s; cursors[e] = s; s += counts[e]; }
    offsets[E] = s;
  }
}

// ---------- build permutation (token list grouped by expert) ----------
__global__ __launch_bounds__(256) void perm_k(const int* __restrict__ idx,
                                              int* __restrict__ cursors,
                                              int* __restrict__ perm) {
  int n = blockIdx.x * 256 + threadIdx.x;
  int e = idx[n];
  int pos = atomicAdd(&cursors[e], 1);
  perm[pos] = n;
}

// ---------- gather x rows in permuted order, convert to bf16 ----------
__global__ __launch_bounds__(256) void gather_x(const float* __restrict__ x,
                                                const int* __restrict__ perm,
                                                u16* __restrict__ xg) {
  int t = blockIdx.x * 256 + threadIdx.x;
  int r = t >> 7;              // 128 threads per row
  int c = (t & 127) << 2;
  float4 v = *(const float4*)(x + (size_t)perm[r] * D + c);
  ushort4 o; o.x = f2b(v.x); o.y = f2b(v.y); o.z = f2b(v.z); o.w = f2b(v.w);
  *(ushort4*)(xg + (size_t)r * D + c) = o;
}

// ---------- transpose+convert: src fp32 [E][R][C] -> dst bf16 [E][C][R] ----------
__global__ __launch_bounds__(256) void transpose_cvt(const float* __restrict__ src,
                                                     u16* __restrict__ dst,
                                                     int R, int C) {
  __shared__ float tile[64][65];
  int e = blockIdx.y;
  int tilesC = C >> 6;
  int bt = blockIdx.x;
  int trow = (bt / tilesC) << 6;
  int tcol = (bt % tilesC) << 6;
  const float* s = src + (size_t)e * R * C;
  u16* d = dst + (size_t)e * R * C;
  int lr = threadIdx.x >> 4;          // 0..15
  int lc = (threadIdx.x & 15) << 2;   // 0..60
#pragma unroll
  for (int i = 0; i < 64; i += 16) {
    float4 v = *(const float4*)(s + (size_t)(trow + lr + i) * C + tcol + lc);
    tile[lr + i][lc + 0] = v.x; tile[lr + i][lc + 1] = v.y;
    tile[lr + i][lc + 2] = v.z; tile[lr + i][lc + 3] = v.w;
  }
  __syncthreads();
#pragma unroll
  for (int i = 0; i < 64; i += 16) {
    int c = lr + i;                   // col of src tile = row of dst
    ushort4 o;
    o.x = f2b(tile[lc + 0][c]); o.y = f2b(tile[lc + 1][c]);
    o.z = f2b(tile[lc + 2][c]); o.w = f2b(tile[lc + 3][c]);
    *(ushort4*)(d + (size_t)(tcol + c) * R + trow + lc) = o;
  }
}

// ---------- grouped GEMM, 128x128 tile, BK=32, 4 waves, 16x16x32 bf16 MFMA ----
// A: bf16 [4096][K] row-major (rows grouped by expert); B: bf16 [E][N][K] (B^T)
// FUSE1: out = relu(acc + bias) -> bf16 Hout[4096][N]
// else : out = acc + bias       -> fp32 Fout[perm[row]][512]
template <int K, int NBLK, bool FUSE1>
__global__ __launch_bounds__(256) void gemm_grouped(
    const u16* __restrict__ A, const u16* __restrict__ B,
    const float* __restrict__ bias, const int* __restrict__ offsets,
    const int* __restrict__ perm, u16* __restrict__ Hout,
    float* __restrict__ Fout) {
  constexpr int N = NBLK * 128;
  __shared__ u16 sA[128 * 32];
  __shared__ u16 sB[128 * 32];

  int bid = blockIdx.x;
  int e = bid / (32 * NBLK);
  int rem = bid % (32 * NBLK);
  int mt = rem / NBLK;
  int nt = rem % NBLK;
  int off = offsets[e];
  int cnt = offsets[e + 1] - off;
  if (mt * 128 >= cnt) return;

  int t = threadIdx.x;
  int l = t & 63;
  int sr = t >> 2;             // 0..63 : row within 64-row half-tile
  int sc = (t & 3) * 8;        // 8-elem chunk within BK=32 row
  int arow0 = off + mt * 128;
  int ga0 = arow0 + sr;       if (ga0 > NTOK - 1) ga0 = NTOK - 1;
  int ga1 = arow0 + 64 + sr;  if (ga1 > NTOK - 1) ga1 = NTOK - 1;
  const u16* Ap0 = A + (size_t)ga0 * K + sc;
  const u16* Ap1 = A + (size_t)ga1 * K + sc;
  const u16* Be = B + ((size_t)e * N + (size_t)nt * 128) * K;
  const u16* Bp0 = Be + (size_t)sr * K + sc;
  const u16* Bp1 = Be + (size_t)(64 + sr) * K + sc;
  u16* dA = &sA[sr * 32 + sc];   // == sA + 8*t : linear in thread id (gload_lds req)
  u16* dB = &sB[sr * 32 + sc];

  int wid = t >> 6;
  int wr = (wid >> 1) * 64;      // wave sub-tile: 64x64
  int wc = (wid & 1) * 64;
  int lm = l & 15;
  int lk = (l >> 4) * 8;

  f32x4 acc[4][4] = {};

  for (int k0 = 0; k0 < K; k0 += 32) {
    gload16(Ap0 + k0, dA);
    gload16(Ap1 + k0, dA + 64 * 32);
    gload16(Bp0 + k0, dB);
    gload16(Bp1 + k0, dB + 64 * 32);
    __syncthreads();
    bf16x8 av[4], bv[4];
#pragma unroll
    for (int fm = 0; fm < 4; ++fm)
      av[fm] = *(const bf16x8*)&sA[(wr + fm * 16 + lm) * 32 + lk];
#pragma unroll
    for (int fn = 0; fn < 4; ++fn)
      bv[fn] = *(const bf16x8*)&sB[(wc + fn * 16 + lm) * 32 + lk];
#pragma unroll
    for (int fm = 0; fm < 4; ++fm)
#pragma unroll
      for (int fn = 0; fn < 4; ++fn)
        acc[fm][fn] = __builtin_amdgcn_mfma_f32_16x16x32_bf16(av[fm], bv[fn],
                                                              acc[fm][fn], 0, 0, 0);
    __syncthreads();
  }

  // epilogue: C/D layout col = lane&15, row = (lane>>4)*4 + reg
  int nbase = nt * 128 + wc;
  float bb[4];
#pragma unroll
  for (int fn = 0; fn < 4; ++fn) bb[fn] = bias[e * N + nbase + fn * 16 + lm];
#pragma unroll
  for (int fm = 0; fm < 4; ++fm) {
    int mbase = wr + fm * 16 + (l >> 4) * 4;
#pragma unroll
    for (int r = 0; r < 4; ++r) {
      int m = mt * 128 + mbase + r;
      if (m < cnt) {
        size_t grow = (size_t)(off + m);
#pragma unroll
        for (int fn = 0; fn < 4; ++fn) {
          float v = acc[fm][fn][r] + bb[fn];
          int n = nbase + fn * 16 + lm;
          if constexpr (FUSE1) {
            Hout[grow * N + n] = f2b(fmaxf(v, 0.f));
          } else {
            Fout[(size_t)perm[grow] * D + n] = v;
          }
        }
      }
    }
  }
}

extern "C" void kernel_launch(void* const* d_in, const int* in_sizes, int n_in,
                              void* d_out, int out_size, void* d_ws, size_t ws_size,
                              hipStream_t stream) {
  const float* x  = (const float*)d_in[0];
  const float* Wg = (const float*)d_in[1];
  const float* bg = (const float*)d_in[2];
  const float* W1 = (const float*)d_in[3];
  const float* b1 = (const float*)d_in[4];
  const float* W2 = (const float*)d_in[5];
  const float* b2 = (const float*)d_in[6];
  float* out = (float*)d_out;
  char* ws = (char*)d_ws;

  int* counts  = (int*)(ws + WS_COUNTS);
  int* offsets = (int*)(ws + WS_OFFSETS);
  int* cursors = (int*)(ws + WS_CURSORS);
  int* idx     = (int*)(ws + WS_IDX);
  int* perm    = (int*)(ws + WS_PERM);
  u16* xg  = (u16*)(ws + WS_XG);
  u16* w1t = (u16*)(ws + WS_W1T);
  u16* w2t = (u16*)(ws + WS_W2T);
  u16* h   = (u16*)(ws + WS_H);

  hipMemsetAsync(counts, 0, 64, stream);
  gate_k<<<NTOK / 4, 256, 0, stream>>>(x, Wg, bg, idx, counts);
  scan_k<<<1, 64, 0, stream>>>(counts, offsets, cursors);
  perm_k<<<NTOK / 256, 256, 0, stream>>>(idx, cursors, perm);
  gather_x<<<NTOK * D / 4 / 256, 256, 0, stream>>>(x, perm, xg);
  transpose_cvt<<<dim3((D / 64) * (F / 64), E), 256, 0, stream>>>(W1, w1t, D, F);
  transpose_cvt<<<dim3((F / 64) * (D / 64), E), 256, 0, stream>>>(W2, w2t, F, D);
  gemm_grouped<D, F / 128, true>
      <<<E * 32 * (F / 128), 256, 0, stream>>>(xg, w1t, b1, offsets, perm, h, nullptr);
  gemm_grouped<F, D / 128, false>
      <<<E * 32 * (D / 128), 256, 0, stream>>>(h, w2t, b2, offsets, perm, nullptr, out);
}

// Round 2
// 259.152 us; speedup vs baseline: 1.0177x; 1.0177x over previous
//
#include <hip/hip_runtime.h>
#include <stdint.h>

#define E 8
#define D 512
#define F 2048
#define NTOK 4096

typedef __attribute__((ext_vector_type(8))) short bf16x8;
typedef __attribute__((ext_vector_type(4))) float f32x4;
typedef unsigned short u16;

// ---------- workspace layout (bytes) ----------
#define WS_COUNTS   0                         // 8 ints (memset to 0)
#define WS_OFFSETS  64                        // 9 ints
#define WS_CURSORS  128                       // 8 ints
#define WS_IDX      256                       // 4096 ints
#define WS_PERM     (256 + 4*NTOK)            // 4096 ints
#define WS_XG       65536                     // bf16 [4096][512]  (gathered x)
#define WS_W1T      (WS_XG + 2*NTOK*D)        // bf16 [8][2048][512]  (W1^T)
#define WS_W2T      (WS_W1T + 2*E*D*F)        // bf16 [8][512][2048]  (W2^T)
#define WS_H        (WS_W2T + 2*E*D*F)        // bf16 [4096][2048]  (hidden)

static __device__ __forceinline__ u16 f2b(float f) {
  union { float f; unsigned u; } v; v.f = f;
  unsigned r = v.u + 0x7fffu + ((v.u >> 16) & 1u);   // RNE fp32->bf16
  return (u16)(r >> 16);
}

static __device__ __forceinline__ void gload16(const void* g, void* l) {
  __builtin_amdgcn_global_load_lds(
      (const __attribute__((address_space(1))) unsigned int*)g,
      (__attribute__((address_space(3))) unsigned int*)l, 16, 0, 0);
}

// ---------- gate: fp32-exact logits + argmax + per-expert count ----------
__global__ __launch_bounds__(256) void gate_k(const float* __restrict__ x,
                                              const float* __restrict__ Wg,
                                              const float* __restrict__ bg,
                                              int* __restrict__ idx,
                                              int* __restrict__ counts) {
  int tok = blockIdx.x * 4 + (threadIdx.x >> 6);   // one wave per token
  int l = threadIdx.x & 63;
  const float* xr = x + (size_t)tok * D;
  float acc[E];
#pragma unroll
  for (int e = 0; e < E; ++e) acc[e] = 0.f;
#pragma unroll
  for (int j = 0; j < 2; ++j) {
    float4 xv = *(const float4*)(xr + l * 8 + j * 4);
    float xs[4] = {xv.x, xv.y, xv.z, xv.w};
#pragma unroll
    for (int c = 0; c < 4; ++c) {
      int d = l * 8 + j * 4 + c;
      float4 w0 = *(const float4*)(Wg + d * 8);
      float4 w1 = *(const float4*)(Wg + d * 8 + 4);
      acc[0] += xs[c] * w0.x; acc[1] += xs[c] * w0.y;
      acc[2] += xs[c] * w0.z; acc[3] += xs[c] * w0.w;
      acc[4] += xs[c] * w1.x; acc[5] += xs[c] * w1.y;
      acc[6] += xs[c] * w1.z; acc[7] += xs[c] * w1.w;
    }
  }
#pragma unroll
  for (int off = 32; off; off >>= 1)
#pragma unroll
    for (int e = 0; e < E; ++e) acc[e] += __shfl_xor(acc[e], off, 64);
  if (l == 0) {
    float bv = acc[0] + bg[0]; int bi = 0;
#pragma unroll
    for (int e = 1; e < E; ++e) {           // strict > : first-max tie-break (matches argmax)
      float v = acc[e] + bg[e];
      if (v > bv) { bv = v; bi = e; }
    }
    idx[tok] = bi;
    atomicAdd(&counts[bi], 1);
  }
}

// ---------- tiny scan: counts -> offsets, cursors ----------
__global__ void scan_k(const int* __restrict__ counts, int* __restrict__ offsets,
                       int* __restrict__ cursors) {
  if (threadIdx.x == 0) {
    int s = 0;
    for (int e = 0; e < E; ++e) { offsets[e] = s; cursors[e] = s; s += counts[e]; }
    offsets[E] = s;
  }
}

// ---------- build permutation (token list grouped by expert) ----------
__global__ __launch_bounds__(256) void perm_k(const int* __restrict__ idx,
                                              int* __restrict__ cursors,
                                              int* __restrict__ perm) {
  int n = blockIdx.x * 256 + threadIdx.x;
  int e = idx[n];
  int pos = atomicAdd(&cursors[e], 1);
  perm[pos] = n;
}

// ---------- gather x rows in permuted order, convert to bf16 ----------
__global__ __launch_bounds__(256) void gather_x(const float* __restrict__ x,
                                                const int* __restrict__ perm,
                                                u16* __restrict__ xg) {
  int t = blockIdx.x * 256 + threadIdx.x;
  int r = t >> 7;              // 128 threads per row
  int c = (t & 127) << 2;
  float4 v = *(const float4*)(x + (size_t)perm[r] * D + c);
  ushort4 o; o.x = f2b(v.x); o.y = f2b(v.y); o.z = f2b(v.z); o.w = f2b(v.w);
  *(ushort4*)(xg + (size_t)r * D + c) = o;
}

// ---------- init out with bias rows: out[n][d] = b2[idx[n]][d] ----------
__global__ __launch_bounds__(256) void out_init(const float* __restrict__ b2,
                                                const int* __restrict__ idx,
                                                float* __restrict__ out) {
  int t = blockIdx.x * 256 + threadIdx.x;
  int n = t >> 7;              // 128 threads per row
  int c = (t & 127) << 2;
  float4 v = *(const float4*)(b2 + (size_t)idx[n] * D + c);
  *(float4*)(out + (size_t)n * D + c) = v;
}

// ---------- transpose+convert: src fp32 [E][R][C] -> dst bf16 [E][C][R] ----------
__global__ __launch_bounds__(256) void transpose_cvt(const float* __restrict__ src,
                                                     u16* __restrict__ dst,
                                                     int R, int C) {
  __shared__ float tile[64][65];
  int e = blockIdx.y;
  int tilesC = C >> 6;
  int bt = blockIdx.x;
  int trow = (bt / tilesC) << 6;
  int tcol = (bt % tilesC) << 6;
  const float* s = src + (size_t)e * R * C;
  u16* d = dst + (size_t)e * R * C;
  int lr = threadIdx.x >> 4;          // 0..15
  int lc = (threadIdx.x & 15) << 2;   // 0..60
#pragma unroll
  for (int i = 0; i < 64; i += 16) {
    float4 v = *(const float4*)(s + (size_t)(trow + lr + i) * C + tcol + lc);
    tile[lr + i][lc + 0] = v.x; tile[lr + i][lc + 1] = v.y;
    tile[lr + i][lc + 2] = v.z; tile[lr + i][lc + 3] = v.w;
  }
  __syncthreads();
#pragma unroll
  for (int i = 0; i < 64; i += 16) {
    int c = lr + i;                   // col of src tile = row of dst
    ushort4 o;
    o.x = f2b(tile[lc + 0][c]); o.y = f2b(tile[lc + 1][c]);
    o.z = f2b(tile[lc + 2][c]); o.w = f2b(tile[lc + 3][c]);
    *(ushort4*)(d + (size_t)(tcol + c) * R + trow + lc) = o;
  }
}

// ---------- grouped GEMM, 128x128 tile, BK=64, double-buffered 2-phase, ----
// ---------- T2 XOR-swizzled LDS, optional split-K                       ----
// A: bf16 [4096][K] row-major (rows grouped by expert); B: bf16 [E][N][K] (B^T)
// FUSE1: out = relu(acc + bias) -> bf16 Hout[4096][N]
// else : atomicAdd(acc)         -> fp32 Fout[perm[row]][512]  (bias pre-init'd)
template <int K, int NBLK, int SPLITK, bool FUSE1>
__global__ __launch_bounds__(256) void gemm_grouped(
    const u16* __restrict__ A, const u16* __restrict__ B,
    const float* __restrict__ bias, const int* __restrict__ offsets,
    const int* __restrict__ perm, u16* __restrict__ Hout,
    float* __restrict__ Fout) {
  constexpr int N = NBLK * 128;
  constexpr int KB = K / SPLITK;          // K handled per block
  constexpr int NT = KB / 64;             // 64-wide K-steps
  __shared__ u16 smem[4 * 8192];          // A0 A1 B0 B1, each 128x64 bf16 (16KB)

  int bid = blockIdx.x;
  int ks = bid % SPLITK;
  int rem = bid / SPLITK;
  int nt = rem % NBLK; rem /= NBLK;
  int mt = rem % 32;
  int e = rem / 32;
  int off = offsets[e];
  int cnt = offsets[e + 1] - off;
  if (mt * 128 >= cnt) return;

  int t = threadIdx.x;
  int w = t >> 6;
  int l = t & 63;

  // ---- staging geometry: per round r (0..3), wave w covers rows r*32+w*8..+8,
  // lane l -> row r*32+w*8+(l>>3), 16B chunk. Source chunk swizzled so that a
  // LINEAR gload_lds dest gives LDS phys chunk p holding logical kc = p^(row&7).
  int rl_base = w * 8 + (l >> 3);
  int cchunk = (l & 7) ^ (l >> 3);        // logical source chunk for phys l&7
  const u16* Ap[4];
  const u16* Bp[4];
  const u16* Beb = B + (size_t)e * N * K + (size_t)(nt * 128) * K + (size_t)ks * KB;
#pragma unroll
  for (int r = 0; r < 4; ++r) {
    int rl = r * 32 + rl_base;
    int ga = off + mt * 128 + rl; if (ga > NTOK - 1) ga = NTOK - 1;
    Ap[r] = A + (size_t)ga * K + (size_t)ks * KB + cchunk * 8;
    Bp[r] = Beb + (size_t)rl * K + cchunk * 8;
  }

  int wr = (w >> 1) * 64;                 // wave output sub-tile 64x64
  int wc = (w & 1) * 64;
  int lm = l & 15;
  int g = l >> 4;

  f32x4 acc[4][4] = {};

  auto stage = [&](int cur, int k0) {
    u16* bA = smem + cur * 8192;
    u16* bB = smem + 16384 + cur * 8192;
#pragma unroll
    for (int r = 0; r < 4; ++r) {
      gload16(Ap[r] + k0, bA + (r * 32 + w * 8) * 64 + l * 8);
      gload16(Bp[r] + k0, bB + (r * 32 + w * 8) * 64 + l * 8);
    }
  };
  auto compute = [&](int cur) {
    const u16* bA = smem + cur * 8192;
    const u16* bB = smem + 16384 + cur * 8192;
#pragma unroll
    for (int kc = 0; kc < 2; ++kc) {
      bf16x8 av[4], bv[4];
#pragma unroll
      for (int fm = 0; fm < 4; ++fm)
        av[fm] = *(const bf16x8*)&bA[(wr + fm * 16 + lm) * 64 +
                                     (((kc * 4 + g) ^ (lm & 7)) * 8)];
#pragma unroll
      for (int fn = 0; fn < 4; ++fn)
        bv[fn] = *(const bf16x8*)&bB[(wc + fn * 16 + lm) * 64 +
                                     (((kc * 4 + g) ^ (lm & 7)) * 8)];
#pragma unroll
      for (int fm = 0; fm < 4; ++fm)
#pragma unroll
        for (int fn = 0; fn < 4; ++fn)
          acc[fm][fn] = __builtin_amdgcn_mfma_f32_16x16x32_bf16(av[fm], bv[fn],
                                                                acc[fm][fn], 0, 0, 0);
    }
  };

  // 2-phase pipeline: STAGE(next) overlaps compute(cur); one barrier per K-step.
  stage(0, 0);
  __syncthreads();
  int cur = 0;
#pragma unroll 2
  for (int tstep = 0; tstep < NT - 1; ++tstep) {
    stage(cur ^ 1, (tstep + 1) * 64);
    compute(cur);
    __syncthreads();
    cur ^= 1;
  }
  compute(cur);

  // epilogue: C/D layout col = lane&15, row = (lane>>4)*4 + reg
  int nbase = nt * 128 + wc;
  float bb[4];
  if constexpr (FUSE1) {
#pragma unroll
    for (int fn = 0; fn < 4; ++fn) bb[fn] = bias[e * N + nbase + fn * 16 + lm];
  }
#pragma unroll
  for (int fm = 0; fm < 4; ++fm) {
    int mbase = wr + fm * 16 + g * 4;
#pragma unroll
    for (int r = 0; r < 4; ++r) {
      int m = mt * 128 + mbase + r;
      if (m < cnt) {
        size_t grow = (size_t)(off + m);
#pragma unroll
        for (int fn = 0; fn < 4; ++fn) {
          int n = nbase + fn * 16 + lm;
          if constexpr (FUSE1) {
            float v = acc[fm][fn][r] + bb[fn];
            Hout[grow * N + n] = f2b(fmaxf(v, 0.f));
          } else {
            atomicAdd(&Fout[(size_t)perm[grow] * D + n], acc[fm][fn][r]);
          }
        }
      }
    }
  }
}

extern "C" void kernel_launch(void* const* d_in, const int* in_sizes, int n_in,
                              void* d_out, int out_size, void* d_ws, size_t ws_size,
                              hipStream_t stream) {
  const float* x  = (const float*)d_in[0];
  const float* Wg = (const float*)d_in[1];
  const float* bg = (const float*)d_in[2];
  const float* W1 = (const float*)d_in[3];
  const float* b1 = (const float*)d_in[4];
  const float* W2 = (const float*)d_in[5];
  const float* b2 = (const float*)d_in[6];
  float* out = (float*)d_out;
  char* ws = (char*)d_ws;

  int* counts  = (int*)(ws + WS_COUNTS);
  int* offsets = (int*)(ws + WS_OFFSETS);
  int* cursors = (int*)(ws + WS_CURSORS);
  int* idx     = (int*)(ws + WS_IDX);
  int* perm    = (int*)(ws + WS_PERM);
  u16* xg  = (u16*)(ws + WS_XG);
  u16* w1t = (u16*)(ws + WS_W1T);
  u16* w2t = (u16*)(ws + WS_W2T);
  u16* h   = (u16*)(ws + WS_H);

  hipMemsetAsync(counts, 0, 64, stream);
  gate_k<<<NTOK / 4, 256, 0, stream>>>(x, Wg, bg, idx, counts);
  scan_k<<<1, 64, 0, stream>>>(counts, offsets, cursors);
  perm_k<<<NTOK / 256, 256, 0, stream>>>(idx, cursors, perm);
  gather_x<<<NTOK * D / 4 / 256, 256, 0, stream>>>(x, perm, xg);
  out_init<<<NTOK * D / 4 / 256, 256, 0, stream>>>(b2, idx, out);
  transpose_cvt<<<dim3((D / 64) * (F / 64), E), 256, 0, stream>>>(W1, w1t, D, F);
  transpose_cvt<<<dim3((F / 64) * (D / 64), E), 256, 0, stream>>>(W2, w2t, F, D);
  gemm_grouped<D, F / 128, 1, true>
      <<<E * 32 * (F / 128), 256, 0, stream>>>(xg, w1t, b1, offsets, perm, h, nullptr);
  gemm_grouped<F, D / 128, 4, false>
      <<<E * 32 * (D / 128) * 4, 256, 0, stream>>>(h, w2t, nullptr, offsets, perm, nullptr, out);
}

// Round 3
// 196.354 us; speedup vs baseline: 1.3431x; 1.3198x over previous
//
#include <hip/hip_runtime.h>
#include <stdint.h>

#define E 8
#define D 512
#define F 2048
#define NTOK 4096

typedef __attribute__((ext_vector_type(8))) short bf16x8;
typedef __attribute__((ext_vector_type(4))) float f32x4;
typedef unsigned short u16;

// ---------- workspace layout (bytes) ----------
#define WS_OFFSETS  64                        // 9 ints
#define WS_IDX      256                       // 4096 ints
#define WS_PERM     (256 + 4*NTOK)            // 4096 ints
#define WS_XG       65536                     // bf16 [4096][512]  (gathered x)
#define WS_W1T      (WS_XG + 2*NTOK*D)        // bf16 [8][2048][512]  (W1^T)
#define WS_W2T      (WS_W1T + 2*E*D*F)        // bf16 [8][512][2048]  (W2^T)
#define WS_H        (WS_W2T + 2*E*D*F)        // bf16 [4096][2048]  (hidden)

static __device__ __forceinline__ u16 f2b(float f) {
  union { float f; unsigned u; } v; v.f = f;
  unsigned r = v.u + 0x7fffu + ((v.u >> 16) & 1u);   // RNE fp32->bf16
  return (u16)(r >> 16);
}

static __device__ __forceinline__ void gload16(const void* g, void* l) {
  __builtin_amdgcn_global_load_lds(
      (const __attribute__((address_space(1))) unsigned int*)g,
      (__attribute__((address_space(3))) unsigned int*)l, 16, 0, 0);
}

// ---------- gate: fp32-exact logits + argmax (NO atomics) ----------
__global__ __launch_bounds__(256) void gate_k(const float* __restrict__ x,
                                              const float* __restrict__ Wg,
                                              const float* __restrict__ bg,
                                              int* __restrict__ idx) {
  int tok = blockIdx.x * 4 + (threadIdx.x >> 6);   // one wave per token
  int l = threadIdx.x & 63;
  const float* xr = x + (size_t)tok * D;
  float acc[E];
#pragma unroll
  for (int e = 0; e < E; ++e) acc[e] = 0.f;
#pragma unroll
  for (int j = 0; j < 2; ++j) {
    float4 xv = *(const float4*)(xr + l * 8 + j * 4);
    float xs[4] = {xv.x, xv.y, xv.z, xv.w};
#pragma unroll
    for (int c = 0; c < 4; ++c) {
      int d = l * 8 + j * 4 + c;
      float4 w0 = *(const float4*)(Wg + d * 8);
      float4 w1 = *(const float4*)(Wg + d * 8 + 4);
      acc[0] += xs[c] * w0.x; acc[1] += xs[c] * w0.y;
      acc[2] += xs[c] * w0.z; acc[3] += xs[c] * w0.w;
      acc[4] += xs[c] * w1.x; acc[5] += xs[c] * w1.y;
      acc[6] += xs[c] * w1.z; acc[7] += xs[c] * w1.w;
    }
  }
#pragma unroll
  for (int off = 32; off; off >>= 1)
#pragma unroll
    for (int e = 0; e < E; ++e) acc[e] += __shfl_xor(acc[e], off, 64);
  if (l == 0) {
    float bv = acc[0] + bg[0]; int bi = 0;
#pragma unroll
    for (int e = 1; e < E; ++e) {           // strict > : first-max tie-break (matches argmax)
      float v = acc[e] + bg[e];
      if (v > bv) { bv = v; bi = e; }
    }
    idx[tok] = bi;
  }
}

// ---------- single block: LDS histogram -> offsets -> permutation ----------
__global__ __launch_bounds__(1024) void hist_perm_k(const int* __restrict__ idx,
                                                    int* __restrict__ offsets,
                                                    int* __restrict__ perm) {
  __shared__ int wcnt[16][E];    // per-wave histograms / later cursors
  __shared__ int wbase[16][E];
  __shared__ int offs[E + 1];
  int t = threadIdx.x;
  int w = t >> 6;
  if (t < 16 * E) ((int*)wcnt)[t] = 0;
  __syncthreads();
  int e0[4];
#pragma unroll
  for (int j = 0; j < 4; ++j) {
    e0[j] = idx[t * 4 + j];
    atomicAdd(&wcnt[w][e0[j]], 1);
  }
  __syncthreads();
  if (t == 0) {
    int s = 0;
    for (int e = 0; e < E; ++e) {
      offs[e] = s;
      int be = s;
      for (int ww = 0; ww < 16; ++ww) { wbase[ww][e] = be; be += wcnt[ww][e]; }
      s = be;
    }
    offs[E] = s;
  }
  __syncthreads();
  if (t < E + 1) offsets[t] = offs[t];
  if (t < 16 * E) ((int*)wcnt)[t] = ((int*)wbase)[t];   // reuse as cursors
  __syncthreads();
#pragma unroll
  for (int j = 0; j < 4; ++j) {
    int pos = atomicAdd(&wcnt[w][e0[j]], 1);
    perm[pos] = t * 4 + j;
  }
}

// ---------- gather x rows in permuted order, convert to bf16 ----------
__global__ __launch_bounds__(256) void gather_x(const float* __restrict__ x,
                                                const int* __restrict__ perm,
                                                u16* __restrict__ xg) {
  int t = blockIdx.x * 256 + threadIdx.x;
  int r = t >> 7;              // 128 threads per row
  int c = (t & 127) << 2;
  float4 v = *(const float4*)(x + (size_t)perm[r] * D + c);
  ushort4 o; o.x = f2b(v.x); o.y = f2b(v.y); o.z = f2b(v.z); o.w = f2b(v.w);
  *(ushort4*)(xg + (size_t)r * D + c) = o;
}

// ---------- init out with bias rows: out[n][d] = b2[idx[n]][d] ----------
__global__ __launch_bounds__(256) void out_init(const float* __restrict__ b2,
                                                const int* __restrict__ idx,
                                                float* __restrict__ out) {
  int t = blockIdx.x * 256 + threadIdx.x;
  int n = t >> 7;              // 128 threads per row
  int c = (t & 127) << 2;
  float4 v = *(const float4*)(b2 + (size_t)idx[n] * D + c);
  *(float4*)(out + (size_t)n * D + c) = v;
}

// ---------- transpose+convert: src fp32 [E][R][C] -> dst bf16 [E][C][R] ----------
__global__ __launch_bounds__(256) void transpose_cvt(const float* __restrict__ src,
                                                     u16* __restrict__ dst,
                                                     int R, int C) {
  __shared__ float tile[64][65];
  int e = blockIdx.y;
  int tilesC = C >> 6;
  int bt = blockIdx.x;
  int trow = (bt / tilesC) << 6;
  int tcol = (bt % tilesC) << 6;
  const float* s = src + (size_t)e * R * C;
  u16* d = dst + (size_t)e * R * C;
  int lr = threadIdx.x >> 4;          // 0..15
  int lc = (threadIdx.x & 15) << 2;   // 0..60
#pragma unroll
  for (int i = 0; i < 64; i += 16) {
    float4 v = *(const float4*)(s + (size_t)(trow + lr + i) * C + tcol + lc);
    tile[lr + i][lc + 0] = v.x; tile[lr + i][lc + 1] = v.y;
    tile[lr + i][lc + 2] = v.z; tile[lr + i][lc + 3] = v.w;
  }
  __syncthreads();
#pragma unroll
  for (int i = 0; i < 64; i += 16) {
    int c = lr + i;                   // col of src tile = row of dst
    ushort4 o;
    o.x = f2b(tile[lc + 0][c]); o.y = f2b(tile[lc + 1][c]);
    o.z = f2b(tile[lc + 2][c]); o.w = f2b(tile[lc + 3][c]);
    *(ushort4*)(d + (size_t)(tcol + c) * R + trow + lc) = o;
  }
}

// ---------- grouped GEMM, 128x128 tile, BK=64, double-buffered 2-phase, ----
// ---------- T2 XOR-swizzled LDS, optional split-K                       ----
// A: bf16 [4096][K] row-major (rows grouped by expert); B: bf16 [E][N][K] (B^T)
// FUSE1: out = relu(acc + bias) -> bf16 Hout[4096][N]
// else : atomicAdd(acc)         -> fp32 Fout[perm[row]][512]  (bias pre-init'd)
template <int K, int NBLK, int SPLITK, bool FUSE1>
__global__ __launch_bounds__(256) void gemm_grouped(
    const u16* __restrict__ A, const u16* __restrict__ B,
    const float* __restrict__ bias, const int* __restrict__ offsets,
    const int* __restrict__ perm, u16* __restrict__ Hout,
    float* __restrict__ Fout) {
  constexpr int N = NBLK * 128;
  constexpr int KB = K / SPLITK;          // K handled per block
  constexpr int NT = KB / 64;             // 64-wide K-steps
  __shared__ u16 smem[4 * 8192];          // A0 A1 B0 B1, each 128x64 bf16 (16KB)

  int bid = blockIdx.x;
  int ks = bid % SPLITK;
  int rem = bid / SPLITK;
  int nt = rem % NBLK; rem /= NBLK;
  int mt = rem % 32;
  int e = rem / 32;
  int off = offsets[e];
  int cnt = offsets[e + 1] - off;
  if (mt * 128 >= cnt) return;

  int t = threadIdx.x;
  int w = t >> 6;
  int l = t & 63;

  // ---- staging geometry: per round r (0..3), wave w covers rows r*32+w*8..+8,
  // lane l -> row r*32+w*8+(l>>3), 16B chunk. Source chunk swizzled so that a
  // LINEAR gload_lds dest gives LDS phys chunk p holding logical kc = p^(row&7).
  int rl_base = w * 8 + (l >> 3);
  int cchunk = (l & 7) ^ (l >> 3);        // logical source chunk for phys l&7
  const u16* Ap[4];
  const u16* Bp[4];
  const u16* Beb = B + (size_t)e * N * K + (size_t)(nt * 128) * K + (size_t)ks * KB;
#pragma unroll
  for (int r = 0; r < 4; ++r) {
    int rl = r * 32 + rl_base;
    int ga = off + mt * 128 + rl; if (ga > NTOK - 1) ga = NTOK - 1;
    Ap[r] = A + (size_t)ga * K + (size_t)ks * KB + cchunk * 8;
    Bp[r] = Beb + (size_t)rl * K + cchunk * 8;
  }

  int wr = (w >> 1) * 64;                 // wave output sub-tile 64x64
  int wc = (w & 1) * 64;
  int lm = l & 15;
  int g = l >> 4;

  f32x4 acc[4][4] = {};

  auto stage = [&](int cur, int k0) {
    u16* bA = smem + cur * 8192;
    u16* bB = smem + 16384 + cur * 8192;
#pragma unroll
    for (int r = 0; r < 4; ++r) {
      gload16(Ap[r] + k0, bA + (r * 32 + w * 8) * 64 + l * 8);
      gload16(Bp[r] + k0, bB + (r * 32 + w * 8) * 64 + l * 8);
    }
  };
  auto compute = [&](int cur) {
    const u16* bA = smem + cur * 8192;
    const u16* bB = smem + 16384 + cur * 8192;
#pragma unroll
    for (int kc = 0; kc < 2; ++kc) {
      bf16x8 av[4], bv[4];
#pragma unroll
      for (int fm = 0; fm < 4; ++fm)
        av[fm] = *(const bf16x8*)&bA[(wr + fm * 16 + lm) * 64 +
                                     (((kc * 4 + g) ^ (lm & 7)) * 8)];
#pragma unroll
      for (int fn = 0; fn < 4; ++fn)
        bv[fn] = *(const bf16x8*)&bB[(wc + fn * 16 + lm) * 64 +
                                     (((kc * 4 + g) ^ (lm & 7)) * 8)];
#pragma unroll
      for (int fm = 0; fm < 4; ++fm)
#pragma unroll
        for (int fn = 0; fn < 4; ++fn)
          acc[fm][fn] = __builtin_amdgcn_mfma_f32_16x16x32_bf16(av[fm], bv[fn],
                                                                acc[fm][fn], 0, 0, 0);
    }
  };

  // 2-phase pipeline: STAGE(next) overlaps compute(cur); one barrier per K-step.
  stage(0, 0);
  __syncthreads();
  int cur = 0;
#pragma unroll 2
  for (int tstep = 0; tstep < NT - 1; ++tstep) {
    stage(cur ^ 1, (tstep + 1) * 64);
    compute(cur);
    __syncthreads();
    cur ^= 1;
  }
  compute(cur);

  // epilogue: C/D layout col = lane&15, row = (lane>>4)*4 + reg
  int nbase = nt * 128 + wc;
  float bb[4];
  if constexpr (FUSE1) {
#pragma unroll
    for (int fn = 0; fn < 4; ++fn) bb[fn] = bias[e * N + nbase + fn * 16 + lm];
  }
#pragma unroll
  for (int fm = 0; fm < 4; ++fm) {
    int mbase = wr + fm * 16 + g * 4;
#pragma unroll
    for (int r = 0; r < 4; ++r) {
      int m = mt * 128 + mbase + r;
      if (m < cnt) {
        size_t grow = (size_t)(off + m);
#pragma unroll
        for (int fn = 0; fn < 4; ++fn) {
          int n = nbase + fn * 16 + lm;
          if constexpr (FUSE1) {
            float v = acc[fm][fn][r] + bb[fn];
            Hout[grow * N + n] = f2b(fmaxf(v, 0.f));
          } else {
            atomicAdd(&Fout[(size_t)perm[grow] * D + n], acc[fm][fn][r]);
          }
        }
      }
    }
  }
}

extern "C" void kernel_launch(void* const* d_in, const int* in_sizes, int n_in,
                              void* d_out, int out_size, void* d_ws, size_t ws_size,
                              hipStream_t stream) {
  const float* x  = (const float*)d_in[0];
  const float* Wg = (const float*)d_in[1];
  const float* bg = (const float*)d_in[2];
  const float* W1 = (const float*)d_in[3];
  const float* b1 = (const float*)d_in[4];
  const float* W2 = (const float*)d_in[5];
  const float* b2 = (const float*)d_in[6];
  float* out = (float*)d_out;
  char* ws = (char*)d_ws;

  int* offsets = (int*)(ws + WS_OFFSETS);
  int* idx     = (int*)(ws + WS_IDX);
  int* perm    = (int*)(ws + WS_PERM);
  u16* xg  = (u16*)(ws + WS_XG);
  u16* w1t = (u16*)(ws + WS_W1T);
  u16* w2t = (u16*)(ws + WS_W2T);
  u16* h   = (u16*)(ws + WS_H);

  gate_k<<<NTOK / 4, 256, 0, stream>>>(x, Wg, bg, idx);
  hist_perm_k<<<1, 1024, 0, stream>>>(idx, offsets, perm);
  gather_x<<<NTOK * D / 4 / 256, 256, 0, stream>>>(x, perm, xg);
  out_init<<<NTOK * D / 4 / 256, 256, 0, stream>>>(b2, idx, out);
  transpose_cvt<<<dim3((D / 64) * (F / 64), E), 256, 0, stream>>>(W1, w1t, D, F);
  transpose_cvt<<<dim3((F / 64) * (D / 64), E), 256, 0, stream>>>(W2, w2t, F, D);
  gemm_grouped<D, F / 128, 1, true>
      <<<E * 32 * (F / 128), 256, 0, stream>>>(xg, w1t, b1, offsets, perm, h, nullptr);
  gemm_grouped<F, D / 128, 4, false>
      <<<E * 32 * (D / 128) * 4, 256, 0, stream>>>(h, w2t, nullptr, offsets, perm, nullptr, out);
}

// Round 4
// 179.182 us; speedup vs baseline: 1.4719x; 1.0958x over previous
//
#include <hip/hip_runtime.h>
#include <stdint.h>

#define E 8
#define D 512
#define F 2048
#define NTOK 4096

typedef __attribute__((ext_vector_type(8))) short bf16x8;
typedef __attribute__((ext_vector_type(4))) float f32x4;
typedef unsigned short u16;

// ---------- workspace layout (bytes) ----------
#define WS_OFFSETS  64                        // 9 ints
#define WS_IDX      256                       // 4096 ints
#define WS_PERM     (256 + 4*NTOK)            // 4096 ints
#define WS_XG       65536                     // bf16 [4096][512]  (gathered x)
#define WS_W1T      (WS_XG + 2*NTOK*D)        // bf16 [8][2048][512]  (W1^T)
#define WS_W2T      (WS_W1T + 2*E*D*F)        // bf16 [8][512][2048]  (W2^T)
#define WS_H        (WS_W2T + 2*E*D*F)        // bf16 [4096][2048]  (hidden)
// P0 overlays xg+w1t (dead after gemm1): splits 0,1. P1 after h: splits 2,3.
#define WS_P0       WS_XG                     // fp32 [2][4096][512]
#define WS_P1       (WS_H + 2*NTOK*F)         // fp32 [2][4096][512]

static __device__ __forceinline__ u16 f2b(float f) {
  union { float f; unsigned u; } v; v.f = f;
  unsigned r = v.u + 0x7fffu + ((v.u >> 16) & 1u);   // RNE fp32->bf16
  return (u16)(r >> 16);
}

static __device__ __forceinline__ void gload16(const void* g, void* l) {
  __builtin_amdgcn_global_load_lds(
      (const __attribute__((address_space(1))) unsigned int*)g,
      (__attribute__((address_space(3))) unsigned int*)l, 16, 0, 0);
}

// ---------- gate: fp32-exact logits + argmax (NO atomics) ----------
__global__ __launch_bounds__(256) void gate_k(const float* __restrict__ x,
                                              const float* __restrict__ Wg,
                                              const float* __restrict__ bg,
                                              int* __restrict__ idx) {
  int tok = blockIdx.x * 4 + (threadIdx.x >> 6);   // one wave per token
  int l = threadIdx.x & 63;
  const float* xr = x + (size_t)tok * D;
  float acc[E];
#pragma unroll
  for (int e = 0; e < E; ++e) acc[e] = 0.f;
#pragma unroll
  for (int j = 0; j < 2; ++j) {
    float4 xv = *(const float4*)(xr + l * 8 + j * 4);
    float xs[4] = {xv.x, xv.y, xv.z, xv.w};
#pragma unroll
    for (int c = 0; c < 4; ++c) {
      int d = l * 8 + j * 4 + c;
      float4 w0 = *(const float4*)(Wg + d * 8);
      float4 w1 = *(const float4*)(Wg + d * 8 + 4);
      acc[0] += xs[c] * w0.x; acc[1] += xs[c] * w0.y;
      acc[2] += xs[c] * w0.z; acc[3] += xs[c] * w0.w;
      acc[4] += xs[c] * w1.x; acc[5] += xs[c] * w1.y;
      acc[6] += xs[c] * w1.z; acc[7] += xs[c] * w1.w;
    }
  }
#pragma unroll
  for (int off = 32; off; off >>= 1)
#pragma unroll
    for (int e = 0; e < E; ++e) acc[e] += __shfl_xor(acc[e], off, 64);
  if (l == 0) {
    float bv = acc[0] + bg[0]; int bi = 0;
#pragma unroll
    for (int e = 1; e < E; ++e) {           // strict > : first-max tie-break (matches argmax)
      float v = acc[e] + bg[e];
      if (v > bv) { bv = v; bi = e; }
    }
    idx[tok] = bi;
  }
}

// ---------- single block: LDS histogram -> offsets -> permutation ----------
__global__ __launch_bounds__(1024) void hist_perm_k(const int* __restrict__ idx,
                                                    int* __restrict__ offsets,
                                                    int* __restrict__ perm) {
  __shared__ int wcnt[16][E];    // per-wave histograms / later cursors
  __shared__ int wbase[16][E];
  __shared__ int offs[E + 1];
  int t = threadIdx.x;
  int w = t >> 6;
  if (t < 16 * E) ((int*)wcnt)[t] = 0;
  __syncthreads();
  int e0[4];
#pragma unroll
  for (int j = 0; j < 4; ++j) {
    e0[j] = idx[t * 4 + j];
    atomicAdd(&wcnt[w][e0[j]], 1);
  }
  __syncthreads();
  if (t == 0) {
    int s = 0;
    for (int e = 0; e < E; ++e) {
      offs[e] = s;
      int be = s;
      for (int ww = 0; ww < 16; ++ww) { wbase[ww][e] = be; be += wcnt[ww][e]; }
      s = be;
    }
    offs[E] = s;
  }
  __syncthreads();
  if (t < E + 1) offsets[t] = offs[t];
  if (t < 16 * E) ((int*)wcnt)[t] = ((int*)wbase)[t];   // reuse as cursors
  __syncthreads();
#pragma unroll
  for (int j = 0; j < 4; ++j) {
    int pos = atomicAdd(&wcnt[w][e0[j]], 1);
    perm[pos] = t * 4 + j;
  }
}

// ---------- gather x rows in permuted order, convert to bf16 ----------
__global__ __launch_bounds__(256) void gather_x(const float* __restrict__ x,
                                                const int* __restrict__ perm,
                                                u16* __restrict__ xg) {
  int t = blockIdx.x * 256 + threadIdx.x;
  int r = t >> 7;              // 128 threads per row
  int c = (t & 127) << 2;
  float4 v = *(const float4*)(x + (size_t)perm[r] * D + c);
  ushort4 o; o.x = f2b(v.x); o.y = f2b(v.y); o.z = f2b(v.z); o.w = f2b(v.w);
  *(ushort4*)(xg + (size_t)r * D + c) = o;
}

// ---------- transpose+convert: src fp32 [E][R][C] -> dst bf16 [E][C][R] ----------
__global__ __launch_bounds__(256) void transpose_cvt(const float* __restrict__ src,
                                                     u16* __restrict__ dst,
                                                     int R, int C) {
  __shared__ float tile[64][65];
  int e = blockIdx.y;
  int tilesC = C >> 6;
  int bt = blockIdx.x;
  int trow = (bt / tilesC) << 6;
  int tcol = (bt % tilesC) << 6;
  const float* s = src + (size_t)e * R * C;
  u16* d = dst + (size_t)e * R * C;
  int lr = threadIdx.x >> 4;          // 0..15
  int lc = (threadIdx.x & 15) << 2;   // 0..60
#pragma unroll
  for (int i = 0; i < 64; i += 16) {
    float4 v = *(const float4*)(s + (size_t)(trow + lr + i) * C + tcol + lc);
    tile[lr + i][lc + 0] = v.x; tile[lr + i][lc + 1] = v.y;
    tile[lr + i][lc + 2] = v.z; tile[lr + i][lc + 3] = v.w;
  }
  __syncthreads();
#pragma unroll
  for (int i = 0; i < 64; i += 16) {
    int c = lr + i;                   // col of src tile = row of dst
    ushort4 o;
    o.x = f2b(tile[lc + 0][c]); o.y = f2b(tile[lc + 1][c]);
    o.z = f2b(tile[lc + 2][c]); o.w = f2b(tile[lc + 3][c]);
    *(ushort4*)(d + (size_t)(tcol + c) * R + trow + lc) = o;
  }
}

// ---------- grouped GEMM, 128x128 tile, BK=64, double-buffered 2-phase, ----
// ---------- T2 XOR-swizzled LDS, optional split-K (partials, no atomics) ----
// A: bf16 [4096][K] row-major (rows grouped by expert); B: bf16 [E][N][K] (B^T)
// FUSE1: out = relu(acc + bias) -> bf16 Hout[4096][N]
// else : plain store acc        -> fp32 P[ks][4096][512] partials
template <int K, int NBLK, int SPLITK, bool FUSE1>
__global__ __launch_bounds__(256) void gemm_grouped(
    const u16* __restrict__ A, const u16* __restrict__ B,
    const float* __restrict__ bias, const int* __restrict__ offsets,
    u16* __restrict__ Hout, float* __restrict__ P0, float* __restrict__ P1) {
  constexpr int N = NBLK * 128;
  constexpr int KB = K / SPLITK;          // K handled per block
  constexpr int NT = KB / 64;             // 64-wide K-steps
  __shared__ u16 smem[4 * 8192];          // A0 A1 B0 B1, each 128x64 bf16 (16KB)

  int bid = blockIdx.x;
  int ks = bid % SPLITK;
  int rem = bid / SPLITK;
  int nt = rem % NBLK; rem /= NBLK;
  int mt = rem % 32;
  int e = rem / 32;
  int off = offsets[e];
  int cnt = offsets[e + 1] - off;
  if (mt * 128 >= cnt) return;

  int t = threadIdx.x;
  int w = t >> 6;
  int l = t & 63;

  // ---- staging geometry: per round r (0..3), wave w covers rows r*32+w*8..+8,
  // lane l -> row r*32+w*8+(l>>3), 16B chunk. Source chunk swizzled so that a
  // LINEAR gload_lds dest gives LDS phys chunk p holding logical kc = p^(row&7).
  int rl_base = w * 8 + (l >> 3);
  int cchunk = (l & 7) ^ (l >> 3);        // logical source chunk for phys l&7
  const u16* Ap[4];
  const u16* Bp[4];
  const u16* Beb = B + (size_t)e * N * K + (size_t)(nt * 128) * K + (size_t)ks * KB;
#pragma unroll
  for (int r = 0; r < 4; ++r) {
    int rl = r * 32 + rl_base;
    int ga = off + mt * 128 + rl; if (ga > NTOK - 1) ga = NTOK - 1;
    Ap[r] = A + (size_t)ga * K + (size_t)ks * KB + cchunk * 8;
    Bp[r] = Beb + (size_t)rl * K + cchunk * 8;
  }

  int wr = (w >> 1) * 64;                 // wave output sub-tile 64x64
  int wc = (w & 1) * 64;
  int lm = l & 15;
  int g = l >> 4;

  f32x4 acc[4][4] = {};

  auto stage = [&](int cur, int k0) {
    u16* bA = smem + cur * 8192;
    u16* bB = smem + 16384 + cur * 8192;
#pragma unroll
    for (int r = 0; r < 4; ++r) {
      gload16(Ap[r] + k0, bA + (r * 32 + w * 8) * 64 + l * 8);
      gload16(Bp[r] + k0, bB + (r * 32 + w * 8) * 64 + l * 8);
    }
  };
  auto compute = [&](int cur) {
    const u16* bA = smem + cur * 8192;
    const u16* bB = smem + 16384 + cur * 8192;
    __builtin_amdgcn_s_setprio(1);
#pragma unroll
    for (int kc = 0; kc < 2; ++kc) {
      bf16x8 av[4], bv[4];
#pragma unroll
      for (int fm = 0; fm < 4; ++fm)
        av[fm] = *(const bf16x8*)&bA[(wr + fm * 16 + lm) * 64 +
                                     (((kc * 4 + g) ^ (lm & 7)) * 8)];
#pragma unroll
      for (int fn = 0; fn < 4; ++fn)
        bv[fn] = *(const bf16x8*)&bB[(wc + fn * 16 + lm) * 64 +
                                     (((kc * 4 + g) ^ (lm & 7)) * 8)];
#pragma unroll
      for (int fm = 0; fm < 4; ++fm)
#pragma unroll
        for (int fn = 0; fn < 4; ++fn)
          acc[fm][fn] = __builtin_amdgcn_mfma_f32_16x16x32_bf16(av[fm], bv[fn],
                                                                acc[fm][fn], 0, 0, 0);
    }
    __builtin_amdgcn_s_setprio(0);
  };

  // 2-phase pipeline: STAGE(next) overlaps compute(cur); one barrier per K-step.
  stage(0, 0);
  __syncthreads();
  int cur = 0;
#pragma unroll 2
  for (int tstep = 0; tstep < NT - 1; ++tstep) {
    stage(cur ^ 1, (tstep + 1) * 64);
    compute(cur);
    __syncthreads();
    cur ^= 1;
  }
  compute(cur);

  // epilogue: C/D layout col = lane&15, row = (lane>>4)*4 + reg
  int nbase = nt * 128 + wc;
  float bb[4];
  if constexpr (FUSE1) {
#pragma unroll
    for (int fn = 0; fn < 4; ++fn) bb[fn] = bias[e * N + nbase + fn * 16 + lm];
  }
  float* Pp = nullptr;
  if constexpr (!FUSE1)
    Pp = (ks < 2) ? P0 + (size_t)ks * (NTOK * D) : P1 + (size_t)(ks - 2) * (NTOK * D);
#pragma unroll
  for (int fm = 0; fm < 4; ++fm) {
    int mbase = wr + fm * 16 + g * 4;
#pragma unroll
    for (int r = 0; r < 4; ++r) {
      int m = mt * 128 + mbase + r;
      if (m < cnt) {
        size_t grow = (size_t)(off + m);
#pragma unroll
        for (int fn = 0; fn < 4; ++fn) {
          int n = nbase + fn * 16 + lm;
          if constexpr (FUSE1) {
            float v = acc[fm][fn][r] + bb[fn];
            Hout[grow * N + n] = f2b(fmaxf(v, 0.f));
          } else {
            Pp[grow * D + n] = acc[fm][fn][r];
          }
        }
      }
    }
  }
}

// ---------- reduce split-K partials + bias, scatter through perm ----------
__global__ __launch_bounds__(256) void reduce_k(const float* __restrict__ P0,
                                                const float* __restrict__ P1,
                                                const float* __restrict__ b2,
                                                const int* __restrict__ offsets,
                                                const int* __restrict__ perm,
                                                float* __restrict__ out) {
  int t = blockIdx.x * 256 + threadIdx.x;
  int g = t >> 7;              // sorted row
  int c = (t & 127) << 2;
  int e = 0;
#pragma unroll
  for (int k = 1; k < E; ++k) e += (g >= offsets[k]);
  size_t pi = (size_t)g * D + c;
  float4 a0 = *(const float4*)(P0 + pi);
  float4 a1 = *(const float4*)(P0 + (size_t)NTOK * D + pi);
  float4 a2 = *(const float4*)(P1 + pi);
  float4 a3 = *(const float4*)(P1 + (size_t)NTOK * D + pi);
  float4 bb = *(const float4*)(b2 + (size_t)e * D + c);
  float4 r;
  r.x = bb.x + ((a0.x + a1.x) + (a2.x + a3.x));
  r.y = bb.y + ((a0.y + a1.y) + (a2.y + a3.y));
  r.z = bb.z + ((a0.z + a1.z) + (a2.z + a3.z));
  r.w = bb.w + ((a0.w + a1.w) + (a2.w + a3.w));
  *(float4*)(out + (size_t)perm[g] * D + c) = r;
}

extern "C" void kernel_launch(void* const* d_in, const int* in_sizes, int n_in,
                              void* d_out, int out_size, void* d_ws, size_t ws_size,
                              hipStream_t stream) {
  const float* x  = (const float*)d_in[0];
  const float* Wg = (const float*)d_in[1];
  const float* bg = (const float*)d_in[2];
  const float* W1 = (const float*)d_in[3];
  const float* b1 = (const float*)d_in[4];
  const float* W2 = (const float*)d_in[5];
  const float* b2 = (const float*)d_in[6];
  float* out = (float*)d_out;
  char* ws = (char*)d_ws;

  int* offsets = (int*)(ws + WS_OFFSETS);
  int* idx     = (int*)(ws + WS_IDX);
  int* perm    = (int*)(ws + WS_PERM);
  u16* xg  = (u16*)(ws + WS_XG);
  u16* w1t = (u16*)(ws + WS_W1T);
  u16* w2t = (u16*)(ws + WS_W2T);
  u16* h   = (u16*)(ws + WS_H);
  float* P0 = (float*)(ws + WS_P0);
  float* P1 = (float*)(ws + WS_P1);

  gate_k<<<NTOK / 4, 256, 0, stream>>>(x, Wg, bg, idx);
  hist_perm_k<<<1, 1024, 0, stream>>>(idx, offsets, perm);
  gather_x<<<NTOK * D / 4 / 256, 256, 0, stream>>>(x, perm, xg);
  transpose_cvt<<<dim3((D / 64) * (F / 64), E), 256, 0, stream>>>(W1, w1t, D, F);
  transpose_cvt<<<dim3((F / 64) * (D / 64), E), 256, 0, stream>>>(W2, w2t, F, D);
  gemm_grouped<D, F / 128, 1, true>
      <<<E * 32 * (F / 128), 256, 0, stream>>>(xg, w1t, b1, offsets, h, nullptr, nullptr);
  gemm_grouped<F, D / 128, 4, false>
      <<<E * 32 * (D / 128) * 4, 256, 0, stream>>>(h, w2t, nullptr, offsets, nullptr, P0, P1);
  reduce_k<<<NTOK * D / 4 / 256, 256, 0, stream>>>(P0, P1, b2, offsets, perm, out);
}

// Round 6
// 177.122 us; speedup vs baseline: 1.4890x; 1.0116x over previous
//
#include <hip/hip_runtime.h>
#include <stdint.h>

#define E 8
#define D 512
#define F 2048
#define NTOK 4096

typedef __attribute__((ext_vector_type(8))) short bf16x8;
typedef __attribute__((ext_vector_type(4))) float f32x4;
typedef unsigned short u16;

// ---------- workspace layout (bytes) ----------
#define WS_OFFSETS  64                        // 9 ints
#define WS_IDX      256                       // 4096 ints
#define WS_PERM     (256 + 4*NTOK)            // 4096 ints
#define WS_XG       65536                     // bf16 [4096][512]  (gathered x)
#define WS_W1T      (WS_XG + 2*NTOK*D)        // bf16 [8][2048][512]  (W1^T)
#define WS_W2T      (WS_W1T + 2*E*D*F)        // bf16 [8][512][2048]  (W2^T)
#define WS_H        (WS_W2T + 2*E*D*F)        // bf16 [4096][2048]  (hidden)
// P0 overlays xg+w1t (dead after gemm1): splits 0,1. P1 after h: splits 2,3.
#define WS_P0       WS_XG                     // fp32 [2][4096][512]
#define WS_P1       (WS_H + 2*NTOK*F)         // fp32 [2][4096][512]

static __device__ __forceinline__ u16 f2b(float f) {
  union { float f; unsigned u; } v; v.f = f;
  unsigned r = v.u + 0x7fffu + ((v.u >> 16) & 1u);   // RNE fp32->bf16
  return (u16)(r >> 16);
}

static __device__ __forceinline__ void gload16(const void* g, void* l) {
  __builtin_amdgcn_global_load_lds(
      (const __attribute__((address_space(1))) unsigned int*)g,
      (__attribute__((address_space(3))) unsigned int*)l, 16, 0, 0);
}

// ---------- gate: fp32-exact logits + argmax (NO atomics) ----------
__global__ __launch_bounds__(256) void gate_k(const float* __restrict__ x,
                                              const float* __restrict__ Wg,
                                              const float* __restrict__ bg,
                                              int* __restrict__ idx) {
  int tok = blockIdx.x * 4 + (threadIdx.x >> 6);   // one wave per token
  int l = threadIdx.x & 63;
  const float* xr = x + (size_t)tok * D;
  float acc[E];
#pragma unroll
  for (int e = 0; e < E; ++e) acc[e] = 0.f;
#pragma unroll
  for (int j = 0; j < 2; ++j) {
    float4 xv = *(const float4*)(xr + l * 8 + j * 4);
    float xs[4] = {xv.x, xv.y, xv.z, xv.w};
#pragma unroll
    for (int c = 0; c < 4; ++c) {
      int d = l * 8 + j * 4 + c;
      float4 w0 = *(const float4*)(Wg + d * 8);
      float4 w1 = *(const float4*)(Wg + d * 8 + 4);
      acc[0] += xs[c] * w0.x; acc[1] += xs[c] * w0.y;
      acc[2] += xs[c] * w0.z; acc[3] += xs[c] * w0.w;
      acc[4] += xs[c] * w1.x; acc[5] += xs[c] * w1.y;
      acc[6] += xs[c] * w1.z; acc[7] += xs[c] * w1.w;
    }
  }
#pragma unroll
  for (int off = 32; off; off >>= 1)
#pragma unroll
    for (int e = 0; e < E; ++e) acc[e] += __shfl_xor(acc[e], off, 64);
  if (l == 0) {
    float bv = acc[0] + bg[0]; int bi = 0;
#pragma unroll
    for (int e = 1; e < E; ++e) {           // strict > : first-max tie-break (matches argmax)
      float v = acc[e] + bg[e];
      if (v > bv) { bv = v; bi = e; }
    }
    idx[tok] = bi;
  }
}

// ---------- single block: LDS histogram -> offsets -> permutation ----------
// Scan is wave-parallel (__shfl_up over 64 lanes, 2 (ww,e) pairs per lane).
__global__ __launch_bounds__(1024) void hist_perm_k(const int* __restrict__ idx,
                                                    int* __restrict__ offsets,
                                                    int* __restrict__ perm) {
  __shared__ int wcnt[16][E];    // per-wave histograms / later cursors
  __shared__ int wbase[16][E];
  __shared__ int offs[E + 1];
  int t = threadIdx.x;
  int w = t >> 6;
  if (t < 16 * E) ((int*)wcnt)[t] = 0;
  __syncthreads();
  int e0[4];
#pragma unroll
  for (int j = 0; j < 4; ++j) {
    e0[j] = idx[t * 4 + j];
    atomicAdd(&wcnt[w][e0[j]], 1);
  }
  __syncthreads();
  if (t < 64) {
    // linear index li = e*16 + ww (expert-major) matches cursor-assignment order
    int li0 = 2 * t, li1 = 2 * t + 1;
    int c0 = wcnt[li0 & 15][li0 >> 4];
    int c1 = wcnt[li1 & 15][li1 >> 4];
    int s = c0 + c1;
    int incl = s;
#pragma unroll
    for (int o = 1; o < 64; o <<= 1) {
      int v = __shfl_up(incl, o, 64);
      if (t >= o) incl += v;
    }
    int excl = incl - s;
    wbase[li0 & 15][li0 >> 4] = excl;
    wbase[li1 & 15][li1 >> 4] = excl + c0;
    if ((li0 & 15) == 0) offs[li0 >> 4] = excl;   // start of expert li0>>4
    if (t == 63) offs[E] = incl;                  // total
  }
  __syncthreads();
  if (t < E + 1) offsets[t] = offs[t];
  if (t < 16 * E) ((int*)wcnt)[t] = ((int*)wbase)[t];   // reuse as cursors
  __syncthreads();
#pragma unroll
  for (int j = 0; j < 4; ++j) {
    int pos = atomicAdd(&wcnt[w][e0[j]], 1);
    perm[pos] = t * 4 + j;
  }
}

// ---------- gather x rows in permuted order, convert to bf16 ----------
__global__ __launch_bounds__(256) void gather_x(const float* __restrict__ x,
                                                const int* __restrict__ perm,
                                                u16* __restrict__ xg) {
  int t = blockIdx.x * 256 + threadIdx.x;
  int r = t >> 7;              // 128 threads per row
  int c = (t & 127) << 2;
  float4 v = *(const float4*)(x + (size_t)perm[r] * D + c);
  ushort4 o; o.x = f2b(v.x); o.y = f2b(v.y); o.z = f2b(v.z); o.w = f2b(v.w);
  *(ushort4*)(xg + (size_t)r * D + c) = o;
}

// ---------- transpose+convert: src fp32 [E][R][C] -> dst bf16 [E][C][R] ----------
__global__ __launch_bounds__(256) void transpose_cvt(const float* __restrict__ src,
                                                     u16* __restrict__ dst,
                                                     int R, int C) {
  __shared__ float tile[64][65];
  int e = blockIdx.y;
  int tilesC = C >> 6;
  int bt = blockIdx.x;
  int trow = (bt / tilesC) << 6;
  int tcol = (bt % tilesC) << 6;
  const float* s = src + (size_t)e * R * C;
  u16* d = dst + (size_t)e * R * C;
  int lr = threadIdx.x >> 4;          // 0..15
  int lc = (threadIdx.x & 15) << 2;   // 0..60
#pragma unroll
  for (int i = 0; i < 64; i += 16) {
    float4 v = *(const float4*)(s + (size_t)(trow + lr + i) * C + tcol + lc);
    tile[lr + i][lc + 0] = v.x; tile[lr + i][lc + 1] = v.y;
    tile[lr + i][lc + 2] = v.z; tile[lr + i][lc + 3] = v.w;
  }
  __syncthreads();
#pragma unroll
  for (int i = 0; i < 64; i += 16) {
    int c = lr + i;                   // col of src tile = row of dst
    ushort4 o;
    o.x = f2b(tile[lc + 0][c]); o.y = f2b(tile[lc + 1][c]);
    o.z = f2b(tile[lc + 2][c]); o.w = f2b(tile[lc + 3][c]);
    *(ushort4*)(d + (size_t)(tcol + c) * R + trow + lc) = o;
  }
}

// ---------- grouped GEMM, 128x128 tile, BK=64, double-buffered 2-phase, ----
// ---------- T2 XOR-swizzled LDS, T1 XCD swizzle, split-K partials        ----
// A: bf16 [4096][K] row-major (rows grouped by expert); B: bf16 [E][N][K] (B^T)
// FUSE1: out = relu(acc + bias) -> bf16 Hout[4096][N]
// else : plain store acc        -> fp32 P[ks][4096][512] partials
template <int K, int NBLK, int SPLITK, bool FUSE1>
__global__ __launch_bounds__(256) void gemm_grouped(
    const u16* __restrict__ A, const u16* __restrict__ B,
    const float* __restrict__ bias, const int* __restrict__ offsets,
    u16* __restrict__ Hout, float* __restrict__ P0, float* __restrict__ P1) {
  constexpr int N = NBLK * 128;
  constexpr int KB = K / SPLITK;          // K handled per block
  constexpr int NT = KB / 64;             // 64-wide K-steps
  __shared__ u16 smem[4 * 8192];          // A0 A1 B0 B1, each 128x64 bf16 (16KB)

  // T1: bijective XCD swizzle (gridDim.x % 8 == 0) so each XCD owns a
  // contiguous run of logical tiles; nt fastest -> neighbors share A-panel.
  int nwg = gridDim.x;
  int b0 = blockIdx.x;
  int bid = (b0 & 7) * (nwg >> 3) + (b0 >> 3);
  int nt = bid % NBLK; int rem = bid / NBLK;
  int ks = rem % SPLITK; rem /= SPLITK;
  int mt = rem % 32;
  int e = rem / 32;
  int off = offsets[e];
  int cnt = offsets[e + 1] - off;
  if (mt * 128 >= cnt) return;

  int t = threadIdx.x;
  int w = t >> 6;
  int l = t & 63;

  // ---- staging geometry: per round r (0..3), wave w covers rows r*32+w*8..+8,
  // lane l -> row r*32+w*8+(l>>3), 16B chunk. Source chunk swizzled so that a
  // LINEAR gload_lds dest gives LDS phys chunk p holding logical kc = p^(row&7).
  int rl_base = w * 8 + (l >> 3);
  int cchunk = (l & 7) ^ (l >> 3);        // logical source chunk for phys l&7
  const u16* Ap[4];
  const u16* Bp[4];
  const u16* Beb = B + (size_t)e * N * K + (size_t)(nt * 128) * K + (size_t)ks * KB;
#pragma unroll
  for (int r = 0; r < 4; ++r) {
    int rl = r * 32 + rl_base;
    int ga = off + mt * 128 + rl; if (ga > NTOK - 1) ga = NTOK - 1;
    Ap[r] = A + (size_t)ga * K + (size_t)ks * KB + cchunk * 8;
    Bp[r] = Beb + (size_t)rl * K + cchunk * 8;
  }

  int wr = (w >> 1) * 64;                 // wave output sub-tile 64x64
  int wc = (w & 1) * 64;
  int lm = l & 15;
  int g = l >> 4;

  f32x4 acc[4][4] = {};

  auto stage = [&](int cur, int k0) {
    u16* bA = smem + cur * 8192;
    u16* bB = smem + 16384 + cur * 8192;
#pragma unroll
    for (int r = 0; r < 4; ++r) {
      gload16(Ap[r] + k0, bA + (r * 32 + w * 8) * 64 + l * 8);
      gload16(Bp[r] + k0, bB + (r * 32 + w * 8) * 64 + l * 8);
    }
  };
  auto compute = [&](int cur) {
    const u16* bA = smem + cur * 8192;
    const u16* bB = smem + 16384 + cur * 8192;
    __builtin_amdgcn_s_setprio(1);
#pragma unroll
    for (int kc = 0; kc < 2; ++kc) {
      bf16x8 av[4], bv[4];
#pragma unroll
      for (int fm = 0; fm < 4; ++fm)
        av[fm] = *(const bf16x8*)&bA[(wr + fm * 16 + lm) * 64 +
                                     (((kc * 4 + g) ^ (lm & 7)) * 8)];
#pragma unroll
      for (int fn = 0; fn < 4; ++fn)
        bv[fn] = *(const bf16x8*)&bB[(wc + fn * 16 + lm) * 64 +
                                     (((kc * 4 + g) ^ (lm & 7)) * 8)];
#pragma unroll
      for (int fm = 0; fm < 4; ++fm)
#pragma unroll
        for (int fn = 0; fn < 4; ++fn)
          acc[fm][fn] = __builtin_amdgcn_mfma_f32_16x16x32_bf16(av[fm], bv[fn],
                                                                acc[fm][fn], 0, 0, 0);
    }
    __builtin_amdgcn_s_setprio(0);
  };

  // 2-phase pipeline: STAGE(next) overlaps compute(cur); one barrier per K-step.
  stage(0, 0);
  __syncthreads();
  int cur = 0;
#pragma unroll 2
  for (int tstep = 0; tstep < NT - 1; ++tstep) {
    stage(cur ^ 1, (tstep + 1) * 64);
    compute(cur);
    __syncthreads();
    cur ^= 1;
  }
  compute(cur);

  // epilogue: C/D layout col = lane&15, row = (lane>>4)*4 + reg
  int nbase = nt * 128 + wc;
  float bb[4];
  if constexpr (FUSE1) {
#pragma unroll
    for (int fn = 0; fn < 4; ++fn) bb[fn] = bias[e * N + nbase + fn * 16 + lm];
  }
  float* Pp = nullptr;
  if constexpr (!FUSE1)
    Pp = (ks < 2) ? P0 + (size_t)ks * (NTOK * D) : P1 + (size_t)(ks - 2) * (NTOK * D);
#pragma unroll
  for (int fm = 0; fm < 4; ++fm) {
    int mbase = wr + fm * 16 + g * 4;
#pragma unroll
    for (int r = 0; r < 4; ++r) {
      int m = mt * 128 + mbase + r;
      if (m < cnt) {
        size_t grow = (size_t)(off + m);
#pragma unroll
        for (int fn = 0; fn < 4; ++fn) {
          int n = nbase + fn * 16 + lm;
          if constexpr (FUSE1) {
            float v = acc[fm][fn][r] + bb[fn];
            Hout[grow * N + n] = f2b(fmaxf(v, 0.f));
          } else {
            Pp[grow * D + n] = acc[fm][fn][r];
          }
        }
      }
    }
  }
}

// ---------- reduce split-K partials + bias, scatter through perm ----------
__global__ __launch_bounds__(256) void reduce_k(const float* __restrict__ P0,
                                                const float* __restrict__ P1,
                                                const float* __restrict__ b2,
                                                const int* __restrict__ offsets,
                                                const int* __restrict__ perm,
                                                float* __restrict__ out) {
  int t = blockIdx.x * 256 + threadIdx.x;
  int g = t >> 7;              // sorted row
  int c = (t & 127) << 2;
  int e = 0;
#pragma unroll
  for (int k = 1; k < E; ++k) e += (g >= offsets[k]);
  size_t pi = (size_t)g * D + c;
  float4 a0 = *(const float4*)(P0 + pi);
  float4 a1 = *(const float4*)(P0 + (size_t)NTOK * D + pi);
  float4 a2 = *(const float4*)(P1 + pi);
  float4 a3 = *(const float4*)(P1 + (size_t)NTOK * D + pi);
  float4 bb = *(const float4*)(b2 + (size_t)e * D + c);
  float4 r;
  r.x = bb.x + ((a0.x + a1.x) + (a2.x + a3.x));
  r.y = bb.y + ((a0.y + a1.y) + (a2.y + a3.y));
  r.z = bb.z + ((a0.z + a1.z) + (a2.z + a3.z));
  r.w = bb.w + ((a0.w + a1.w) + (a2.w + a3.w));
  *(float4*)(out + (size_t)perm[g] * D + c) = r;
}

extern "C" void kernel_launch(void* const* d_in, const int* in_sizes, int n_in,
                              void* d_out, int out_size, void* d_ws, size_t ws_size,
                              hipStream_t stream) {
  const float* x  = (const float*)d_in[0];
  const float* Wg = (const float*)d_in[1];
  const float* bg = (const float*)d_in[2];
  const float* W1 = (const float*)d_in[3];
  const float* b1 = (const float*)d_in[4];
  const float* W2 = (const float*)d_in[5];
  const float* b2 = (const float*)d_in[6];
  float* out = (float*)d_out;
  char* ws = (char*)d_ws;

  int* offsets = (int*)(ws + WS_OFFSETS);
  int* idx     = (int*)(ws + WS_IDX);
  int* perm    = (int*)(ws + WS_PERM);
  u16* xg  = (u16*)(ws + WS_XG);
  u16* w1t = (u16*)(ws + WS_W1T);
  u16* w2t = (u16*)(ws + WS_W2T);
  u16* h   = (u16*)(ws + WS_H);
  float* P0 = (float*)(ws + WS_P0);
  float* P1 = (float*)(ws + WS_P1);

  gate_k<<<NTOK / 4, 256, 0, stream>>>(x, Wg, bg, idx);
  hist_perm_k<<<1, 1024, 0, stream>>>(idx, offsets, perm);
  gather_x<<<NTOK * D / 4 / 256, 256, 0, stream>>>(x, perm, xg);
  transpose_cvt<<<dim3((D / 64) * (F / 64), E), 256, 0, stream>>>(W1, w1t, D, F);
  transpose_cvt<<<dim3((F / 64) * (D / 64), E), 256, 0, stream>>>(W2, w2t, F, D);
  gemm_grouped<D, F / 128, 1, true>
      <<<E * 32 * (F / 128), 256, 0, stream>>>(xg, w1t, b1, offsets, h, nullptr, nullptr);
  gemm_grouped<F, D / 128, 4, false>
      <<<E * 32 * (D / 128) * 4, 256, 0, stream>>>(h, w2t, nullptr, offsets, nullptr, P0, P1);
  reduce_k<<<NTOK * D / 4 / 256, 256, 0, stream>>>(P0, P1, b2, offsets, perm, out);
}